// Round 22
// baseline (1353.347 us; speedup 1.0000x reference)
//
#include <hip/hip_runtime.h>

#define T_  512
#define B_  128
#define D_  512
#define H_  512
#define N4H 2048
#define NBR 256         // persistent blocks (1 per CU, residency guaranteed)

typedef _Float16 half8  __attribute__((ext_vector_type(8)));
typedef _Float16 half4v __attribute__((ext_vector_type(4)));
typedef float    f32x4  __attribute__((ext_vector_type(4)));

#if __has_builtin(__builtin_amdgcn_global_load_lds)
#define ASYNC_LDS 1
#endif

// ---------- ins f32 -> f16 mirror ----------
__global__ void cvt_ins(const float* __restrict__ in, _Float16* __restrict__ out) {
    int i = blockIdx.x * 256 + threadIdx.x;            // group of 4 elems
    float4 v = ((const float4*)in)[i];
    half4v o;
    o[0] = (_Float16)v.x; o[1] = (_Float16)v.y;
    o[2] = (_Float16)v.z; o[3] = (_Float16)v.w;
    ((half4v*)out)[i] = o;
}

// ---------- fused weight converts ----------
__global__ void cvt_weights(const float* __restrict__ Wi, const float* __restrict__ Wh,
                            _Float16* __restrict__ WiT, _Float16* __restrict__ WhgT) {
    const int bid = blockIdx.x;
    if (bid < 4096) {                                  // WiT[n][k] = Wi[k][n]
        int i = bid * 256 + threadIdx.x;
        int k = i >> 11, n = i & 2047;
        WiT[n * D_ + k] = (_Float16)Wi[i];
    } else {                                           // lane-linear WhgT
        int i = (bid - 4096) * 256 + threadIdx.x;
        int k = i >> 11, c = i & 2047;
        int g = c >> 9, j = c & 511;
        int cp16 = (j >> 4) * 4 + g;
        int jlo = j & 15;
        int ks = k >> 5, kg = (k >> 3) & 3, e = k & 7;
        WhgT[(size_t)cp16 * 8192 + ks * 512 + (kg * 16 + jlo) * 8 + e] = (_Float16)Wh[i];
    }
}

// ---------- helpers ----------
__device__ __forceinline__ void store_c_pair(_Float16* p, float a, float b2) {
    union { unsigned int u; _Float16 h[2]; } x; x.h[0] = (_Float16)a; x.h[1] = (_Float16)b2;
    __hip_atomic_store((unsigned int*)p, x.u, __ATOMIC_RELAXED, __HIP_MEMORY_SCOPE_AGENT);
}
__device__ __forceinline__ void store_h_pair(_Float16* p, float a, float b2) {
    union { unsigned int u; _Float16 h[2]; } x; x.h[0] = (_Float16)a; x.h[1] = (_Float16)b2;
    __hip_atomic_store((unsigned int*)p, x.u, __ATOMIC_RELAXED, __HIP_MEMORY_SCOPE_AGENT);
}
__device__ __forceinline__ float load_c(const _Float16* p) { return (float)*p; }

// ---------- phase 1: Zg = XH @ WiT^T + bias; reset rows fused to gates ----------
__global__ __launch_bounds__(256) void gemm_xwi(const _Float16* __restrict__ XH,
                                                const _Float16* __restrict__ WT,
                                                const float* __restrict__ bv,
                                                const int* __restrict__ resets,
                                                _Float16* __restrict__ Zg,
                                                _Float16* __restrict__ cgrid,
                                                _Float16* __restrict__ hF,
                                                float* __restrict__ out) {
    __shared__ __attribute__((aligned(16))) _Float16 As[128 * 32];
    __shared__ __attribute__((aligned(16))) _Float16 Bs[128 * 32];
    __shared__ __attribute__((aligned(16))) _Float16 Cs[128 * 128];   // 32KB transpose buf
    const int tid  = threadIdx.x;
    const int lane = tid & 63;
    const int wid  = tid >> 6;
    const int wm   = wid >> 1, wn = wid & 1;
    const int bm   = blockIdx.x, bn = blockIdx.y;
    float* ys = out + 2 * (B_ * H_);

    f32x4 acc[4][4];
    for (int m = 0; m < 4; ++m)
        for (int n = 0; n < 4; ++n)
            acc[m][n] = (f32x4){0.f, 0.f, 0.f, 0.f};

    const _Float16* Xb = XH + (size_t)bm * 128 * D_;

    for (int kt = 0; kt < D_ / 32; ++kt) {
        if (kt) __syncthreads();
        #pragma unroll
        for (int s = 0; s < 2; ++s) {
            int idx = tid + s * 256;
            int row = idx >> 2, cg = idx & 3;          // row = tile-col tc for B
            const int wcol = (row >> 5) * 512 + bn * 32 + (row & 31);
#ifdef ASYNC_LDS
            __builtin_amdgcn_global_load_lds(
                (const __attribute__((address_space(1))) void*)(WT + (size_t)wcol * D_ + kt * 32 + cg * 8),
                (__attribute__((address_space(3))) void*)&Bs[idx * 8], 16, 0, 0);
            __builtin_amdgcn_global_load_lds(
                (const __attribute__((address_space(1))) void*)(Xb + (size_t)row * D_ + kt * 32 + cg * 8),
                (__attribute__((address_space(3))) void*)&As[idx * 8], 16, 0, 0);
#else
            *(half8*)&Bs[idx * 8] = *(const half8*)&WT[(size_t)wcol * D_ + kt * 32 + cg * 8];
            *(half8*)&As[idx * 8] = *(const half8*)&Xb[(size_t)row * D_ + kt * 32 + cg * 8];
#endif
        }
        __syncthreads();                               // drains vmcnt: both tiles landed
        half8 a[4], b[4];
        #pragma unroll
        for (int m = 0; m < 4; ++m)
            a[m] = *(const half8*)&As[(wm * 64 + m * 16 + (lane & 15)) * 32 + (lane >> 4) * 8];
        #pragma unroll
        for (int n = 0; n < 4; ++n)
            b[n] = *(const half8*)&Bs[(wn * 64 + n * 16 + (lane & 15)) * 32 + (lane >> 4) * 8];
        #pragma unroll
        for (int m = 0; m < 4; ++m)
            #pragma unroll
            for (int n = 0; n < 4; ++n)
                acc[m][n] = __builtin_amdgcn_mfma_f32_16x16x32_f16(a[m], b[n], acc[m][n], 0, 0, 0);
    }

    // epilogue: acc -> Cs (transpose to [r][jj*4+g])
    const int jlo = lane & 15, kg = lane >> 4;
    float biasv[4];
    #pragma unroll
    for (int n = 0; n < 4; ++n) {
        const int tc = wn * 64 + n * 16 + jlo;
        biasv[n] = bv[(tc >> 5) * 512 + bn * 32 + (tc & 31)];
    }
    #pragma unroll
    for (int m = 0; m < 4; ++m)
        #pragma unroll
        for (int n = 0; n < 4; ++n) {
            const int tc = wn * 64 + n * 16 + jlo;
            const int cj = (tc & 31) * 4 + (tc >> 5);  // jj*4+g
            #pragma unroll
            for (int e = 0; e < 4; ++e) {
                const int rl = wm * 64 + m * 16 + kg * 4 + e;
                Cs[rl * 128 + cj] = (_Float16)(acc[m][n][e] + biasv[n]);
            }
        }
    __syncthreads();

    // write-out: reset rows -> gates (ys/cgrid/hF/out), non-reset -> Zg coalesced
    #pragma unroll
    for (int p = 0; p < 8; ++p) {
        const int row = p * 16 + (tid >> 4);
        const int u   = tid & 15;
        const int it  = bm * 128 + row;                // t*B + b
        const half8 cv = *(const half8*)&Cs[row * 128 + u * 8];
        if (resets[it]) {
            const int t = it >> 7, b = it & 127;
            const int j0 = bn * 32 + u * 2;
            float cn[2], hn[2];
            #pragma unroll
            for (int q = 0; q < 2; ++q) {
                float ig = 1.f / (1.f + __expf(-(float)cv[q * 4 + 0]));
                float gg = 1.f - 2.f / (1.f + __expf(2.f * (float)cv[q * 4 + 2]));
                float og = 1.f / (1.f + __expf(-(float)cv[q * 4 + 3]));
                cn[q] = ig * gg;                       // c_in = 0 (reset)
                hn[q] = og * (1.f - 2.f / (1.f + __expf(2.f * cn[q])));
            }
            *(float2*)&ys[(size_t)it * 512 + j0] = (float2){hn[0], hn[1]};
            {   // f16 h mirror for next-round staging (plain store: cross-kernel boundary)
                union { unsigned int uu; _Float16 h[2]; } hp;
                hp.h[0] = (_Float16)hn[0]; hp.h[1] = (_Float16)hn[1];
                *(unsigned int*)&hF[(size_t)it * 512 + j0] = hp.uu;
            }
            if (t < T_ - 1) {
                union { unsigned int uu; _Float16 h[2]; } cp;
                cp.h[0] = (_Float16)cn[0]; cp.h[1] = (_Float16)cn[1];
                *(unsigned int*)&cgrid[((size_t)(t + 1) * B_ + b) * 512 + j0] = cp.uu;
            } else {
                out[b * 512 + j0] = cn[0];            out[b * 512 + j0 + 1] = cn[1];
                out[B_ * H_ + b * 512 + j0] = hn[0];  out[B_ * H_ + b * 512 + j0 + 1] = hn[1];
            }
        } else {
            *(half8*)&Zg[(size_t)it * N4H + bn * 128 + u * 8] = cv;
        }
    }
}

// ---------- segment analysis ----------
__global__ void seg_analysis(const int* __restrict__ resets, unsigned short* __restrict__ rkey,
                             int* __restrict__ round_off, int* __restrict__ cursors,
                             int* __restrict__ maxr, int* __restrict__ flags) {
    __shared__ int cnt[513];
    const int tid = threadIdx.x;
    for (int i = tid; i < 513; i += 256) cnt[i] = 0;
    for (int i = tid; i < NBR * 32 + 32; i += 256) flags[i] = 0;   // incl. epoch word
    __syncthreads();
    if (tid < 128) {
        int run = 0;
        for (int t = 0; t < T_; ++t) {
            int key;
            if (resets[t * B_ + tid]) { key = 0; run = 0; }
            else                      { run += 1; key = run; }
            rkey[t * B_ + tid] = (unsigned short)key;
            atomicAdd(&cnt[key], 1);
        }
    }
    __syncthreads();
    if (tid == 0) {
        int off = 0, mx = 0;
        for (int d = 0; d <= 512; ++d) {
            round_off[d] = off;
            cursors[d]   = off;
            if (cnt[d]) mx = d;
            off += cnt[d];
        }
        round_off[513] = off;
        *maxr = mx;
    }
}

__global__ void seg_scatter(const unsigned short* __restrict__ rkey,
                            int* __restrict__ cursors, int* __restrict__ items) {
    __shared__ int lcnt[513];
    __shared__ int lbase[513];
    const int tid = threadIdx.x;
    for (int i = tid; i < 513; i += 256) lcnt[i] = 0;
    __syncthreads();
    const int i = blockIdx.x * 256 + tid;              // 65536 total
    const int key = rkey[i];
    const int lpos = atomicAdd(&lcnt[key], 1);
    __syncthreads();
    for (int k = tid; k < 513; k += 256)
        if (lcnt[k]) lbase[k] = atomicAdd(&cursors[k], lcnt[k]);
    __syncthreads();
    items[lbase[key] + lpos] = i;
}

// ---------- hierarchical epoch barrier ----------
__device__ __forceinline__ void gbar(int* flags, int bid, int tid, int phase) {
    int* epoch = &flags[NBR * 32];
    __syncthreads();                   // drains vmcnt: block's MALL stores ack'd
    if (tid == 0)
        __hip_atomic_store(&flags[bid * 32], phase, __ATOMIC_RELAXED, __HIP_MEMORY_SCOPE_AGENT);
    if (bid == 0) {
        if (tid < 64) {
            for (;;) {
                int mn = 0x7fffffff;
                #pragma unroll
                for (int s = 0; s < NBR / 64; ++s) {
                    int v = __hip_atomic_load(&flags[(tid + 64 * s) * 32], __ATOMIC_RELAXED, __HIP_MEMORY_SCOPE_AGENT);
                    mn = min(mn, v);
                }
                if (__all(mn >= phase)) break;
                __builtin_amdgcn_s_sleep(1);
            }
        }
        if (tid == 0)
            __hip_atomic_store(epoch, phase, __ATOMIC_RELAXED, __HIP_MEMORY_SCOPE_AGENT);
    } else {
        if (tid == 0)
            while (__hip_atomic_load(epoch, __ATOMIC_RELAXED, __HIP_MEMORY_SCOPE_AGENT) < phase)
                __builtin_amdgcn_s_sleep(1);
    }
    __syncthreads();
}

// ---------- phase 2: depth-round scan; hF f16 staging via global_load_lds ----------
__global__ __launch_bounds__(512) void lstm_rounds(const _Float16* __restrict__ Zg,
                                                   const _Float16* __restrict__ WhgT,
                                                   const float* __restrict__ c0,
                                                   const float* __restrict__ h0,
                                                   const int* __restrict__ items,
                                                   const int* __restrict__ round_off,
                                                   const int* __restrict__ maxr_p,
                                                   _Float16* __restrict__ cgrid,   // [512][B][512] f16
                                                   _Float16* __restrict__ hF,      // [512*B][512] f16
                                                   float* __restrict__ out,
                                                   int* __restrict__ flags) {
    const int bid  = blockIdx.x;
    const int tid  = threadIdx.x;
    const int lane = tid & 63;
    const int wg   = tid >> 8;                 // wavegroup 0/1
    const int ltid = tid & 255;                // id within group
    const int lw   = ltid >> 6;                // wave within group 0..3
    float* ys = out + 2 * (B_ * H_);
    __shared__ _Float16 As[2][64 * 512];       // 2 x 64KB, chunk-XOR swizzled
    __shared__ int itS[2][64];

    const int maxr = *maxr_p;
    for (int r = 1; r <= maxr; ++r) {
        const int roff = round_off[r];
        const int N = round_off[r + 1] - roff;
        const int ntiles = ((N + 63) >> 6) * 4;        // item-tiles x 4 col-tiles
        for (int base = bid * 2; base < ntiles; base += NBR * 2) {
            const int tile = base + wg;
            const bool act = tile < ntiles;
            const int ct = tile & 3;
            const int rbase = (tile >> 2) * 64;
            __syncthreads();                           // prior tile readers done (both groups)
            if (act) {
                // stage A: one wave per row; LDS dst linear (lane*16B), XOR on SOURCE chunk
                for (int rr16 = 0; rr16 < 16; ++rr16) {
                    const int row = lw * 16 + rr16;
                    const int rr = rbase + row;
                    if (rr >= N) continue;             // wave-uniform
                    const int it = items[roff + rr];   // broadcast load
                    if (lane == 0) itS[wg][row] = it;
                    const int t = it >> 7, b = it & 127;
                    const int sc = lane ^ (row & 7);   // source chunk for this lane
                    if (t == 0) {                      // h from f32 h0 (round-1 only, rare)
                        const float* src = h0 + b * 512 + sc * 8;
                        float4 f0 = *(const float4*)src, f1 = *(const float4*)(src + 4);
                        half8 hv;
                        hv[0]=(_Float16)f0.x; hv[1]=(_Float16)f0.y; hv[2]=(_Float16)f0.z; hv[3]=(_Float16)f0.w;
                        hv[4]=(_Float16)f1.x; hv[5]=(_Float16)f1.y; hv[6]=(_Float16)f1.z; hv[7]=(_Float16)f1.w;
                        *(half8*)&As[wg][(row * 64 + lane) * 8] = hv;
                    } else {
#ifdef ASYNC_LDS
                        __builtin_amdgcn_global_load_lds(
                            (const __attribute__((address_space(1))) void*)(hF + (size_t)((t - 1) * B_ + b) * 512 + sc * 8),
                            (__attribute__((address_space(3))) void*)&As[wg][(row * 64 + lane) * 8], 16, 0, 0);
#else
                        *(half8*)&As[wg][(row * 64 + lane) * 8] =
                            *(const half8*)&hF[(size_t)((t - 1) * B_ + b) * 512 + sc * 8];
#endif
                    }
                }
            }
            __syncthreads();                           // drains vmcnt (async) + lgkm
            if (!act) continue;

            const int jlo = lane & 15, kg = lane >> 4;
            const int colw16 = ct * 32 + lw * 8;       // cp16 base for this wave

            #pragma unroll
            for (int jh = 0; jh < 2; ++jh) {
                const int j = (ct * 8 + lw * 2 + jh) * 16 + jlo;

                // ---- prefetch epilogue inputs (cold-HBM Zg + cgrid) under MFMA ----
                half4v g4p[4][4];
                float  cip[4][4];
                #pragma unroll
                for (int m = 0; m < 4; ++m)
                    #pragma unroll
                    for (int e = 0; e < 4; ++e) {
                        const int rr = rbase + m * 16 + kg * 4 + e;
                        if (rr < N) {
                            const int it = itS[wg][rr - rbase];
                            const int t = it >> 7, b = it & 127;
                            g4p[m][e] = *(const half4v*)&Zg[(size_t)it * N4H + j * 4];
                            cip[m][e] = (t == 0) ? c0[b * 512 + j]
                                                 : load_c(&cgrid[((size_t)t * B_ + b) * 512 + j]);
                        }
                    }

                f32x4 acc[4][4];
                #pragma unroll
                for (int m = 0; m < 4; ++m)
                    #pragma unroll
                    for (int f = 0; f < 4; ++f) acc[m][f] = (f32x4){0.f, 0.f, 0.f, 0.f};

                #pragma unroll 2
                for (int ks = 0; ks < 16; ++ks) {
                    half8 av[4];
                    #pragma unroll
                    for (int m = 0; m < 4; ++m) {
                        const int row = m * 16 + jlo;
                        av[m] = *(const half8*)&As[wg][(row * 64 + ((ks * 4 + kg) ^ (row & 7))) * 8];
                    }
                    #pragma unroll
                    for (int fc = 0; fc < 4; ++fc) {
                        const half8 bv8 = *(const half8*)&WhgT[(size_t)(colw16 + jh * 4 + fc) * 8192 + ks * 512 + lane * 8];
                        #pragma unroll
                        for (int m = 0; m < 4; ++m)
                            acc[m][fc] = __builtin_amdgcn_mfma_f32_16x16x32_f16(av[m], bv8, acc[m][fc], 0, 0, 0);
                    }
                }

                // ---- epilogue for this jh half (inputs already in registers) ----
                #pragma unroll
                for (int m = 0; m < 4; ++m) {
                    #pragma unroll
                    for (int e = 0; e < 4; ++e) {
                        const int rr = rbase + m * 16 + kg * 4 + e;
                        if (rr < N) {
                            const int it = itS[wg][rr - rbase];
                            const int t = it >> 7, b = it & 127;
                            float zv[4];
                            #pragma unroll
                            for (int g = 0; g < 4; ++g)
                                zv[g] = acc[m][g][e] + (float)g4p[m][e][g];
                            const float ci = cip[m][e];
                            float ig = 1.f / (1.f + __expf(-zv[0]));
                            float fg = 1.f / (1.f + __expf(-zv[1]));
                            float gg = 1.f - 2.f / (1.f + __expf(2.f * zv[2]));
                            float og = 1.f / (1.f + __expf(-zv[3]));
                            float cn = fg * ci + ig * gg;
                            float hn = og * (1.f - 2.f / (1.f + __expf(2.f * cn)));
                            float cn1 = __shfl_down(cn, 1);
                            float hn1 = __shfl_down(hn, 1);
                            if (!(jlo & 1)) {          // even lane stores the pair
                                union { unsigned long long u64; float f[2]; } yp;
                                yp.f[0] = hn; yp.f[1] = hn1;
                                __hip_atomic_store((unsigned long long*)&ys[((size_t)t * B_ + b) * 512 + j],
                                                   yp.u64, __ATOMIC_RELAXED, __HIP_MEMORY_SCOPE_AGENT);
                                store_h_pair(&hF[(size_t)it * 512 + j], hn, hn1);
                                if (t < T_ - 1) {
                                    store_c_pair(&cgrid[((size_t)(t + 1) * B_ + b) * 512 + j], cn, cn1);
                                } else {
                                    out[b * 512 + j] = cn;            out[b * 512 + j + 1] = cn1;
                                    out[B_ * H_ + b * 512 + j] = hn;  out[B_ * H_ + b * 512 + j + 1] = hn1;
                                }
                            }
                        }
                    }
                }
            }
        }
        gbar(flags, bid, tid, r + 1);
    }
}

// ---------- fallback: all-f32 fused ----------
__global__ __launch_bounds__(512) void lstm_fb(const float* __restrict__ ins,
                                               const int* __restrict__ resets,
                                               const float* __restrict__ c0,
                                               const float* __restrict__ h0,
                                               const float* __restrict__ Wi,
                                               const float* __restrict__ Wh,
                                               const float* __restrict__ bv,
                                               float* __restrict__ out) {
    const int b = blockIdx.x;
    const int j = threadIdx.x;
    __shared__ float hs[H_];
    __shared__ float xs[D_];
    float c = c0[b * H_ + j];
    hs[j] = h0[b * H_ + j];
    const float b0 = bv[j], b1 = bv[H_ + j], b2 = bv[2 * H_ + j], b3 = bv[3 * H_ + j];
    float* ys = out + 2 * B_ * H_;
    for (int t = 0; t < T_; ++t) {
        __syncthreads();
        xs[j] = ins[((size_t)(t * B_ + b)) * D_ + j];
        __syncthreads();
        const bool rst = resets[t * B_ + b] != 0;
        float z0 = b0, z1 = b1, z2 = b2, z3 = b3;
        for (int k = 0; k < D_; ++k) {
            float xk = xs[k];
            z0 += xk * Wi[(size_t)k * N4H + j];
            z1 += xk * Wi[(size_t)k * N4H + H_ + j];
            z2 += xk * Wi[(size_t)k * N4H + 2 * H_ + j];
            z3 += xk * Wi[(size_t)k * N4H + 3 * H_ + j];
        }
        float c_use = rst ? 0.f : c;
        if (!rst) {
            for (int k = 0; k < H_; ++k) {
                float hk = hs[k];
                z0 += hk * Wh[(size_t)k * N4H + j];
                z1 += hk * Wh[(size_t)k * N4H + H_ + j];
                z2 += hk * Wh[(size_t)k * N4H + 2 * H_ + j];
                z3 += hk * Wh[(size_t)k * N4H + 3 * H_ + j];
            }
        }
        float ig = 1.f / (1.f + __expf(-z0));
        float fg = 1.f / (1.f + __expf(-z1));
        float gg = 1.f - 2.f / (1.f + __expf(2.f * z2));
        float og = 1.f / (1.f + __expf(-z3));
        c = fg * c_use + ig * gg;
        float h = og * (1.f - 2.f / (1.f + __expf(2.f * c)));
        __syncthreads();
        hs[j] = h;
        ys[((size_t)(t * B_ + b)) * H_ + j] = h;
    }
    out[b * H_ + j] = c;
    out[B_ * H_ + b * H_ + j] = hs[j];
}

extern "C" void kernel_launch(void* const* d_in, const int* in_sizes, int n_in,
                              void* d_out, int out_size, void* d_ws, size_t ws_size,
                              hipStream_t stream) {
    const float* ins    = (const float*)d_in[0];
    const int*   resets = (const int*)d_in[1];
    const float* c0     = (const float*)d_in[2];
    const float* h0     = (const float*)d_in[3];
    const float* Wi     = (const float*)d_in[4];
    const float* Wh     = (const float*)d_in[5];
    const float* bv     = (const float*)d_in[6];
    float*       out    = (float*)d_out;

    const size_t MiB = 1ull << 20;
    // f16 cgrid(64) | WiT(2) | WhgT(2) | Zg(256) | XH(64) | hF(64) | meta(0.5) = 452.5MB
    const size_t o_c    = 0;
    const size_t o_wit  = 64 * MiB;
    const size_t o_whg  = 66 * MiB;
    const size_t o_zg   = 68 * MiB;
    const size_t o_xh   = 324 * MiB;
    const size_t o_hf   = 388 * MiB;
    const size_t o_meta = 452 * MiB;
    const size_t need   = o_meta + 512 * 1024;

    if (ws_size >= need) {
        char* ws = (char*)d_ws;
        _Float16* cgrid = (_Float16*)(ws + o_c);
        _Float16* WiT   = (_Float16*)(ws + o_wit);
        _Float16* WhgT  = (_Float16*)(ws + o_whg);
        _Float16* Zg    = (_Float16*)(ws + o_zg);
        _Float16* XH    = (_Float16*)(ws + o_xh);
        _Float16* hF    = (_Float16*)(ws + o_hf);
        unsigned short* rkey = (unsigned short*)(ws + o_meta);
        int* items     = (int*)(ws + o_meta + 0x20000);
        int* round_off = (int*)(ws + o_meta + 0x60000);
        int* cursors   = (int*)(ws + o_meta + 0x61000);
        int* maxr      = (int*)(ws + o_meta + 0x62000);
        int* flags     = (int*)(ws + o_meta + 0x63000);   // NBR*32 + epoch

        cvt_ins<<<(T_ * B_ * D_ / 4) / 256, 256, 0, stream>>>(ins, XH);
        cvt_weights<<<8192, 256, 0, stream>>>(Wi, Wh, WiT, WhgT);
        seg_analysis<<<1, 256, 0, stream>>>(resets, rkey, round_off, cursors, maxr, flags);
        seg_scatter<<<256, 256, 0, stream>>>(rkey, cursors, items);
        gemm_xwi<<<dim3(T_ * B_ / 128, N4H / 128), 256, 0, stream>>>(
            XH, WiT, bv, resets, Zg, cgrid, hF, out);
        lstm_rounds<<<NBR, 512, 0, stream>>>(Zg, WhgT, c0, h0, items, round_off,
                                             maxr, cgrid, hF, out, flags);
    } else {
        lstm_fb<<<B_, H_, 0, stream>>>(ins, resets, c0, h0, Wi, Wh, bv, out);
    }
}

// Round 23
// 1206.572 us; speedup vs baseline: 1.1216x; 1.1216x over previous
//
#include <hip/hip_runtime.h>

#define T_  512
#define B_  128
#define D_  512
#define H_  512
#define N4H 2048
#define NBR 256         // persistent blocks (1 per CU, residency guaranteed)

typedef _Float16 half8  __attribute__((ext_vector_type(8)));
typedef _Float16 half4v __attribute__((ext_vector_type(4)));
typedef float    f32x4  __attribute__((ext_vector_type(4)));

#if __has_builtin(__builtin_amdgcn_global_load_lds)
#define ASYNC_LDS 1
#endif

// ---------- ins f32 -> f16 mirror ----------
__global__ void cvt_ins(const float* __restrict__ in, _Float16* __restrict__ out) {
    int i = blockIdx.x * 256 + threadIdx.x;            // group of 4 elems
    float4 v = ((const float4*)in)[i];
    half4v o;
    o[0] = (_Float16)v.x; o[1] = (_Float16)v.y;
    o[2] = (_Float16)v.z; o[3] = (_Float16)v.w;
    ((half4v*)out)[i] = o;
}

// ---------- fused weight converts ----------
__global__ void cvt_weights(const float* __restrict__ Wi, const float* __restrict__ Wh,
                            _Float16* __restrict__ WiT, _Float16* __restrict__ WhgT) {
    const int bid = blockIdx.x;
    if (bid < 4096) {                                  // WiT[n][k] = Wi[k][n]
        int i = bid * 256 + threadIdx.x;
        int k = i >> 11, n = i & 2047;
        WiT[n * D_ + k] = (_Float16)Wi[i];
    } else {                                           // lane-linear WhgT
        int i = (bid - 4096) * 256 + threadIdx.x;
        int k = i >> 11, c = i & 2047;
        int g = c >> 9, j = c & 511;
        int cp16 = (j >> 4) * 4 + g;
        int jlo = j & 15;
        int ks = k >> 5, kg = (k >> 3) & 3, e = k & 7;
        WhgT[(size_t)cp16 * 8192 + ks * 512 + (kg * 16 + jlo) * 8 + e] = (_Float16)Wh[i];
    }
}

// ---------- helpers ----------
__device__ __forceinline__ void store_c_pair(float* p, float a, float b2) {
    union { unsigned long long u; float f[2]; } x; x.f[0] = a; x.f[1] = b2;
    __hip_atomic_store((unsigned long long*)p, x.u, __ATOMIC_RELAXED, __HIP_MEMORY_SCOPE_AGENT);
}
__device__ __forceinline__ void store_c_pair(_Float16* p, float a, float b2) {
    union { unsigned int u; _Float16 h[2]; } x; x.h[0] = (_Float16)a; x.h[1] = (_Float16)b2;
    __hip_atomic_store((unsigned int*)p, x.u, __ATOMIC_RELAXED, __HIP_MEMORY_SCOPE_AGENT);
}
__device__ __forceinline__ float load_c(const float* p)    { return *p; }
__device__ __forceinline__ float load_c(const _Float16* p) { return (float)*p; }

// ---------- phase 1: Zg = XH @ WiT^T + bias; reset rows fused to gates ----------
template<typename CT>
__global__ __launch_bounds__(256) void gemm_xwi(const _Float16* __restrict__ XH,
                                                const _Float16* __restrict__ WT,
                                                const float* __restrict__ bv,
                                                const int* __restrict__ resets,
                                                _Float16* __restrict__ Zg,
                                                CT* __restrict__ cgrid,
                                                float* __restrict__ out) {
    __shared__ __attribute__((aligned(16))) _Float16 As[128 * 32];
    __shared__ __attribute__((aligned(16))) _Float16 Bs[128 * 32];
    __shared__ __attribute__((aligned(16))) _Float16 Cs[128 * 128];   // 32KB transpose buf
    const int tid  = threadIdx.x;
    const int lane = tid & 63;
    const int wid  = tid >> 6;
    const int wm   = wid >> 1, wn = wid & 1;
    const int bm   = blockIdx.x, bn = blockIdx.y;
    float* ys = out + 2 * (B_ * H_);

    f32x4 acc[4][4];
    for (int m = 0; m < 4; ++m)
        for (int n = 0; n < 4; ++n)
            acc[m][n] = (f32x4){0.f, 0.f, 0.f, 0.f};

    const _Float16* Xb = XH + (size_t)bm * 128 * D_;

    for (int kt = 0; kt < D_ / 32; ++kt) {
        if (kt) __syncthreads();
        #pragma unroll
        for (int s = 0; s < 2; ++s) {
            int idx = tid + s * 256;
            int row = idx >> 2, cg = idx & 3;          // row = tile-col tc for B
            const int wcol = (row >> 5) * 512 + bn * 32 + (row & 31);
#ifdef ASYNC_LDS
            __builtin_amdgcn_global_load_lds(
                (const __attribute__((address_space(1))) void*)(WT + (size_t)wcol * D_ + kt * 32 + cg * 8),
                (__attribute__((address_space(3))) void*)&Bs[idx * 8], 16, 0, 0);
            __builtin_amdgcn_global_load_lds(
                (const __attribute__((address_space(1))) void*)(Xb + (size_t)row * D_ + kt * 32 + cg * 8),
                (__attribute__((address_space(3))) void*)&As[idx * 8], 16, 0, 0);
#else
            *(half8*)&Bs[idx * 8] = *(const half8*)&WT[(size_t)wcol * D_ + kt * 32 + cg * 8];
            *(half8*)&As[idx * 8] = *(const half8*)&Xb[(size_t)row * D_ + kt * 32 + cg * 8];
#endif
        }
        __syncthreads();                               // drains vmcnt: both tiles landed
        half8 a[4], b[4];
        #pragma unroll
        for (int m = 0; m < 4; ++m)
            a[m] = *(const half8*)&As[(wm * 64 + m * 16 + (lane & 15)) * 32 + (lane >> 4) * 8];
        #pragma unroll
        for (int n = 0; n < 4; ++n)
            b[n] = *(const half8*)&Bs[(wn * 64 + n * 16 + (lane & 15)) * 32 + (lane >> 4) * 8];
        #pragma unroll
        for (int m = 0; m < 4; ++m)
            #pragma unroll
            for (int n = 0; n < 4; ++n)
                acc[m][n] = __builtin_amdgcn_mfma_f32_16x16x32_f16(a[m], b[n], acc[m][n], 0, 0, 0);
    }

    // epilogue: acc -> Cs (transpose to [r][jj*4+g])
    const int jlo = lane & 15, kg = lane >> 4;
    float biasv[4];
    #pragma unroll
    for (int n = 0; n < 4; ++n) {
        const int tc = wn * 64 + n * 16 + jlo;
        biasv[n] = bv[(tc >> 5) * 512 + bn * 32 + (tc & 31)];
    }
    #pragma unroll
    for (int m = 0; m < 4; ++m)
        #pragma unroll
        for (int n = 0; n < 4; ++n) {
            const int tc = wn * 64 + n * 16 + jlo;
            const int cj = (tc & 31) * 4 + (tc >> 5);  // jj*4+g
            #pragma unroll
            for (int e = 0; e < 4; ++e) {
                const int rl = wm * 64 + m * 16 + kg * 4 + e;
                Cs[rl * 128 + cj] = (_Float16)(acc[m][n][e] + biasv[n]);
            }
        }
    __syncthreads();

    // write-out: reset rows -> gates (ys/cgrid/out), non-reset -> Zg coalesced
    #pragma unroll
    for (int p = 0; p < 8; ++p) {
        const int row = p * 16 + (tid >> 4);
        const int u   = tid & 15;
        const int it  = bm * 128 + row;                // t*B + b
        const half8 cv = *(const half8*)&Cs[row * 128 + u * 8];
        if (resets[it]) {
            const int t = it >> 7, b = it & 127;
            const int j0 = bn * 32 + u * 2;
            float cn[2], hn[2];
            #pragma unroll
            for (int q = 0; q < 2; ++q) {
                float ig = 1.f / (1.f + __expf(-(float)cv[q * 4 + 0]));
                float gg = 1.f - 2.f / (1.f + __expf(2.f * (float)cv[q * 4 + 2]));
                float og = 1.f / (1.f + __expf(-(float)cv[q * 4 + 3]));
                cn[q] = ig * gg;                       // c_in = 0 (reset)
                hn[q] = og * (1.f - 2.f / (1.f + __expf(2.f * cn[q])));
            }
            *(float2*)&ys[(size_t)it * 512 + j0] = (float2){hn[0], hn[1]};
            if (t < T_ - 1) {
                store_c_pair(&cgrid[((size_t)(t + 1) * B_ + b) * 512 + j0], cn[0], cn[1]);
            } else {
                out[b * 512 + j0] = cn[0];            out[b * 512 + j0 + 1] = cn[1];
                out[B_ * H_ + b * 512 + j0] = hn[0];  out[B_ * H_ + b * 512 + j0 + 1] = hn[1];
            }
        } else {
            *(half8*)&Zg[(size_t)it * N4H + bn * 128 + u * 8] = cv;
        }
    }
}

// ---------- segment analysis ----------
__global__ void seg_analysis(const int* __restrict__ resets, unsigned short* __restrict__ rkey,
                             int* __restrict__ round_off, int* __restrict__ cursors,
                             int* __restrict__ maxr, int* __restrict__ flags) {
    __shared__ int cnt[513];
    const int tid = threadIdx.x;
    for (int i = tid; i < 513; i += 256) cnt[i] = 0;
    for (int i = tid; i < NBR * 32; i += 256) flags[i] = 0;
    __syncthreads();
    if (tid < 128) {
        int run = 0;
        for (int t = 0; t < T_; ++t) {
            int key;
            if (resets[t * B_ + tid]) { key = 0; run = 0; }
            else                      { run += 1; key = run; }
            rkey[t * B_ + tid] = (unsigned short)key;
            atomicAdd(&cnt[key], 1);
        }
    }
    __syncthreads();
    if (tid == 0) {
        int off = 0, mx = 0;
        for (int d = 0; d <= 512; ++d) {
            round_off[d] = off;
            cursors[d]   = off;
            if (cnt[d]) mx = d;
            off += cnt[d];
        }
        round_off[513] = off;
        *maxr = mx;
    }
}

__global__ void seg_scatter(const unsigned short* __restrict__ rkey,
                            int* __restrict__ cursors, int* __restrict__ items) {
    __shared__ int lcnt[513];
    __shared__ int lbase[513];
    const int tid = threadIdx.x;
    for (int i = tid; i < 513; i += 256) lcnt[i] = 0;
    __syncthreads();
    const int i = blockIdx.x * 256 + tid;              // 65536 total
    const int key = rkey[i];
    const int lpos = atomicAdd(&lcnt[key], 1);
    __syncthreads();
    for (int k = tid; k < 513; k += 256)
        if (lcnt[k]) lbase[k] = atomicAdd(&cursors[k], lcnt[k]);
    __syncthreads();
    items[lbase[key] + lpos] = i;
}

__device__ __forceinline__ void gbar(int* flags, int bid, int tid, int phase) {
    __syncthreads();                   // drains vmcnt: block's MALL stores ack'd
    if (tid == 0)
        __hip_atomic_store(&flags[bid * 32], phase, __ATOMIC_RELAXED, __HIP_MEMORY_SCOPE_AGENT);
    if (tid < 64) {
        for (;;) {
            int mn = 0x7fffffff;
            #pragma unroll
            for (int s = 0; s < NBR / 64; ++s) {
                int v = __hip_atomic_load(&flags[(tid + 64 * s) * 32], __ATOMIC_RELAXED, __HIP_MEMORY_SCOPE_AGENT);
                mn = min(mn, v);
            }
            if (__all(mn >= phase)) break;
            __builtin_amdgcn_s_sleep(1);
        }
    }
    __syncthreads();
}

// ---------- phase 2: depth-round scan (rounds >= 1; round 0 fused into gemm) ----------
template<typename CT>
__global__ __launch_bounds__(512) void lstm_rounds(const _Float16* __restrict__ Zg,
                                                   const _Float16* __restrict__ WhgT,
                                                   const float* __restrict__ c0,
                                                   const float* __restrict__ h0,
                                                   const int* __restrict__ items,
                                                   const int* __restrict__ round_off,
                                                   const int* __restrict__ maxr_p,
                                                   CT* __restrict__ cgrid,   // [512][B][512], [t]=c_{t-1}
                                                   float* __restrict__ out,
                                                   int* __restrict__ flags) {
    const int bid  = blockIdx.x;
    const int tid  = threadIdx.x;
    const int lane = tid & 63;
    const int wg   = tid >> 8;                 // wavegroup 0/1
    const int ltid = tid & 255;                // id within group
    const int lw   = ltid >> 6;                // wave within group 0..3
    float* ys = out + 2 * (B_ * H_);
    __shared__ _Float16 As[2][64 * 512];       // 2 x 64KB, chunk-XOR swizzled
    __shared__ int itS[2][64];

    // ---- GEMM rounds: each wavegroup owns one tile per iteration ----
    const int maxr = *maxr_p;
    for (int r = 1; r <= maxr; ++r) {
        const int roff = round_off[r];
        const int N = round_off[r + 1] - roff;
        const int ntiles = ((N + 63) >> 6) * 4;        // item-tiles x 4 col-tiles
        for (int base = bid * 2; base < ntiles; base += NBR * 2) {
            const int tile = base + wg;
            const bool act = tile < ntiles;
            const int ct = tile & 3;
            const int rbase = (tile >> 2) * 64;
            __syncthreads();                           // prior tile readers done (both groups)
            if (act) {  // stage A [64 rows x 512 k] f16, swizzle: chunk ^= (row&7)
                const int row = ltid >> 2, cq = ltid & 3;
                const int rr = rbase + row;
                if (rr < N) {
                    const int it = items[roff + rr];
                    if (cq == 0) itS[wg][row] = it;
                    const int t = it >> 7, b = it & 127;
                    const float* src = (t == 0) ? (h0 + b * 512)
                                                : (ys + ((size_t)(t - 1) * B_ + b) * 512);
                    #pragma unroll
                    for (int uu = 0; uu < 16; ++uu) {
                        const int ch = cq * 16 + uu;
                        float4 f0 = *(const float4*)(src + ch * 8);
                        float4 f1 = *(const float4*)(src + ch * 8 + 4);
                        half8 hv;
                        hv[0]=(_Float16)f0.x; hv[1]=(_Float16)f0.y; hv[2]=(_Float16)f0.z; hv[3]=(_Float16)f0.w;
                        hv[4]=(_Float16)f1.x; hv[5]=(_Float16)f1.y; hv[6]=(_Float16)f1.z; hv[7]=(_Float16)f1.w;
                        *(half8*)&As[wg][(row * 64 + (ch ^ (row & 7))) * 8] = hv;
                    }
                }
            }
            __syncthreads();
            if (!act) continue;

            const int jlo = lane & 15, kg = lane >> 4;
            const int colw16 = ct * 32 + lw * 8;       // cp16 base for this wave

            #pragma unroll
            for (int jh = 0; jh < 2; ++jh) {
                const int j = (ct * 8 + lw * 2 + jh) * 16 + jlo;

                // ---- prefetch epilogue inputs (cold-HBM Zg + cgrid) under MFMA ----
                half4v g4p[4][4];
                float  cip[4][4];
                #pragma unroll
                for (int m = 0; m < 4; ++m)
                    #pragma unroll
                    for (int e = 0; e < 4; ++e) {
                        const int rr = rbase + m * 16 + kg * 4 + e;
                        if (rr < N) {
                            const int it = itS[wg][rr - rbase];
                            const int t = it >> 7, b = it & 127;
                            g4p[m][e] = *(const half4v*)&Zg[(size_t)it * N4H + j * 4];
                            cip[m][e] = (t == 0) ? c0[b * 512 + j]
                                                 : load_c(&cgrid[((size_t)t * B_ + b) * 512 + j]);
                        }
                    }

                f32x4 acc[4][4];
                #pragma unroll
                for (int m = 0; m < 4; ++m)
                    #pragma unroll
                    for (int f = 0; f < 4; ++f) acc[m][f] = (f32x4){0.f, 0.f, 0.f, 0.f};

                #pragma unroll 2
                for (int ks = 0; ks < 16; ++ks) {
                    half8 av[4];
                    #pragma unroll
                    for (int m = 0; m < 4; ++m) {
                        const int row = m * 16 + jlo;
                        av[m] = *(const half8*)&As[wg][(row * 64 + ((ks * 4 + kg) ^ (row & 7))) * 8];
                    }
                    #pragma unroll
                    for (int fc = 0; fc < 4; ++fc) {
                        const half8 bv8 = *(const half8*)&WhgT[(size_t)(colw16 + jh * 4 + fc) * 8192 + ks * 512 + lane * 8];
                        #pragma unroll
                        for (int m = 0; m < 4; ++m)
                            acc[m][fc] = __builtin_amdgcn_mfma_f32_16x16x32_f16(av[m], bv8, acc[m][fc], 0, 0, 0);
                    }
                }

                // ---- epilogue for this jh half (inputs already in registers) ----
                #pragma unroll
                for (int m = 0; m < 4; ++m) {
                    #pragma unroll
                    for (int e = 0; e < 4; ++e) {
                        const int rr = rbase + m * 16 + kg * 4 + e;
                        if (rr < N) {
                            const int it = itS[wg][rr - rbase];
                            const int t = it >> 7, b = it & 127;
                            float zv[4];
                            #pragma unroll
                            for (int g = 0; g < 4; ++g)
                                zv[g] = acc[m][g][e] + (float)g4p[m][e][g];
                            const float ci = cip[m][e];
                            float ig = 1.f / (1.f + __expf(-zv[0]));
                            float fg = 1.f / (1.f + __expf(-zv[1]));
                            float gg = 1.f - 2.f / (1.f + __expf(2.f * zv[2]));
                            float og = 1.f / (1.f + __expf(-zv[3]));
                            float cn = fg * ci + ig * gg;
                            float hn = og * (1.f - 2.f / (1.f + __expf(2.f * cn)));
                            float cn1 = __shfl_down(cn, 1);
                            float hn1 = __shfl_down(hn, 1);
                            if (!(jlo & 1)) {          // even lane stores the pair
                                union { unsigned long long u64; float f[2]; } yp;
                                yp.f[0] = hn; yp.f[1] = hn1;
                                __hip_atomic_store((unsigned long long*)&ys[((size_t)t * B_ + b) * 512 + j],
                                                   yp.u64, __ATOMIC_RELAXED, __HIP_MEMORY_SCOPE_AGENT);
                                if (t < T_ - 1) {
                                    store_c_pair(&cgrid[((size_t)(t + 1) * B_ + b) * 512 + j], cn, cn1);
                                } else {
                                    out[b * 512 + j] = cn;            out[b * 512 + j + 1] = cn1;
                                    out[B_ * H_ + b * 512 + j] = hn;  out[B_ * H_ + b * 512 + j + 1] = hn1;
                                }
                            }
                        }
                    }
                }
            }
        }
        gbar(flags, bid, tid, r + 1);
    }
}

// ---------- fallback: all-f32 fused ----------
__global__ __launch_bounds__(512) void lstm_fb(const float* __restrict__ ins,
                                               const int* __restrict__ resets,
                                               const float* __restrict__ c0,
                                               const float* __restrict__ h0,
                                               const float* __restrict__ Wi,
                                               const float* __restrict__ Wh,
                                               const float* __restrict__ bv,
                                               float* __restrict__ out) {
    const int b = blockIdx.x;
    const int j = threadIdx.x;
    __shared__ float hs[H_];
    __shared__ float xs[D_];
    float c = c0[b * H_ + j];
    hs[j] = h0[b * H_ + j];
    const float b0 = bv[j], b1 = bv[H_ + j], b2 = bv[2 * H_ + j], b3 = bv[3 * H_ + j];
    float* ys = out + 2 * B_ * H_;
    for (int t = 0; t < T_; ++t) {
        __syncthreads();
        xs[j] = ins[((size_t)(t * B_ + b)) * D_ + j];
        __syncthreads();
        const bool rst = resets[t * B_ + b] != 0;
        float z0 = b0, z1 = b1, z2 = b2, z3 = b3;
        for (int k = 0; k < D_; ++k) {
            float xk = xs[k];
            z0 += xk * Wi[(size_t)k * N4H + j];
            z1 += xk * Wi[(size_t)k * N4H + H_ + j];
            z2 += xk * Wi[(size_t)k * N4H + 2 * H_ + j];
            z3 += xk * Wi[(size_t)k * N4H + 3 * H_ + j];
        }
        float c_use = rst ? 0.f : c;
        if (!rst) {
            for (int k = 0; k < H_; ++k) {
                float hk = hs[k];
                z0 += hk * Wh[(size_t)k * N4H + j];
                z1 += hk * Wh[(size_t)k * N4H + H_ + j];
                z2 += hk * Wh[(size_t)k * N4H + 2 * H_ + j];
                z3 += hk * Wh[(size_t)k * N4H + 3 * H_ + j];
            }
        }
        float ig = 1.f / (1.f + __expf(-z0));
        float fg = 1.f / (1.f + __expf(-z1));
        float gg = 1.f - 2.f / (1.f + __expf(2.f * z2));
        float og = 1.f / (1.f + __expf(-z3));
        c = fg * c_use + ig * gg;
        float h = og * (1.f - 2.f / (1.f + __expf(2.f * c)));
        __syncthreads();
        hs[j] = h;
        ys[((size_t)(t * B_ + b)) * H_ + j] = h;
    }
    out[b * H_ + j] = c;
    out[B_ * H_ + b * H_ + j] = hs[j];
}

extern "C" void kernel_launch(void* const* d_in, const int* in_sizes, int n_in,
                              void* d_out, int out_size, void* d_ws, size_t ws_size,
                              hipStream_t stream) {
    const float* ins    = (const float*)d_in[0];
    const int*   resets = (const int*)d_in[1];
    const float* c0     = (const float*)d_in[2];
    const float* h0     = (const float*)d_in[3];
    const float* Wi     = (const float*)d_in[4];
    const float* Wh     = (const float*)d_in[5];
    const float* bv     = (const float*)d_in[6];
    float*       out    = (float*)d_out;

    const size_t MiB = 1ull << 20;
    const size_t sz_meta = 512 * 1024;

    // variant A: f32 cgrid (preferred). XH (64MB) lives in its own region
    // (cgrid is written by gemm, so XH may NOT overlay cgrid).
    size_t a_c = 0, a_wit = 128 * MiB, a_whg = 130 * MiB, a_zg = 132 * MiB, a_meta = 388 * MiB;
    size_t a_xh = a_meta + sz_meta;                        // 388.5MB .. 452.5MB
    size_t need_a = a_xh + 64 * MiB;
    // variant B: f16 cgrid
    size_t b_c = 0, b_wit = 64 * MiB, b_whg = 66 * MiB, b_zg = 68 * MiB, b_meta = 64 * MiB;
    size_t b_xh = b_zg + 256 * MiB;                        // 324MB .. 388MB
    size_t need_b = b_xh + 64 * MiB;

    const bool useA = ws_size >= need_a;
    const bool useB = !useA && ws_size >= need_b;
    if (useA || useB) {
        char* ws = (char*)d_ws;
        size_t o_c = useA ? a_c : b_c, o_wit = useA ? a_wit : b_wit;
        size_t o_whg = useA ? a_whg : b_whg, o_zg = useA ? a_zg : b_zg;
        size_t o_meta = useA ? a_meta : b_meta;
        size_t o_xh = useA ? a_xh : b_xh;

        _Float16* XH   = (_Float16*)(ws + o_xh);
        _Float16* WiT  = (_Float16*)(ws + o_wit);
        _Float16* WhgT = (_Float16*)(ws + o_whg);
        _Float16* Zg   = (_Float16*)(ws + o_zg);
        unsigned short* rkey = (unsigned short*)(ws + o_meta);
        int* items     = (int*)(ws + o_meta + 0x20000);
        int* round_off = (int*)(ws + o_meta + 0x60000);
        int* cursors   = (int*)(ws + o_meta + 0x61000);
        int* maxr      = (int*)(ws + o_meta + 0x62000);
        int* flags     = (int*)(ws + o_meta + 0x63000);

        cvt_ins<<<(T_ * B_ * D_ / 4) / 256, 256, 0, stream>>>(ins, XH);
        cvt_weights<<<8192, 256, 0, stream>>>(Wi, Wh, WiT, WhgT);
        seg_analysis<<<1, 256, 0, stream>>>(resets, rkey, round_off, cursors, maxr, flags);
        seg_scatter<<<256, 256, 0, stream>>>(rkey, cursors, items);
        if (useA) {
            gemm_xwi<float><<<dim3(T_ * B_ / 128, N4H / 128), 256, 0, stream>>>(
                XH, WiT, bv, resets, Zg, (float*)(ws + o_c), out);
            lstm_rounds<float><<<NBR, 512, 0, stream>>>(Zg, WhgT, c0, h0, items, round_off,
                                                        maxr, (float*)(ws + o_c), out, flags);
        } else {
            gemm_xwi<_Float16><<<dim3(T_ * B_ / 128, N4H / 128), 256, 0, stream>>>(
                XH, WiT, bv, resets, Zg, (_Float16*)(ws + o_c), out);
            lstm_rounds<_Float16><<<NBR, 512, 0, stream>>>(Zg, WhgT, c0, h0, items, round_off,
                                                           maxr, (_Float16*)(ws + o_c), out, flags);
        }
    } else {
        lstm_fb<<<B_, H_, 0, stream>>>(ins, resets, c0, h0, Wi, Wh, bv, out);
    }
}